// Round 6
// baseline (8447.038 us; speedup 1.0000x reference)
//
#include <hip/hip_runtime.h>

constexpr int G   = 8;
constexpr int NN  = 50000;
constexpr int EE  = 800000;
constexpr int F   = 128;
constexpr int NB  = 49;      // dst>>10 buckets (49*1024 >= 50000)
constexpr int CAP = 18432;   // bucket capacity (E[16327] + >10 sigma)
constexpr int PB  = 4;       // blocks per bucket in phase-2 fill

typedef float  float4_t __attribute__((ext_vector_type(4)));
typedef float  f32x4    __attribute__((ext_vector_type(4)));
typedef __bf16 bf16x8   __attribute__((ext_vector_type(8)));
typedef unsigned short u16x4 __attribute__((ext_vector_type(4)));
typedef unsigned short u16x8 __attribute__((ext_vector_type(8)));

__device__ inline float bf2f(unsigned short u) {
  union { unsigned int i; float f; } v; v.i = (unsigned int)u << 16; return v.f;
}
__device__ inline unsigned short f2bf(float f) {
  union { __bf16 b; unsigned short u; } v; v.b = (__bf16)f; return v.u;   // RNE
}
__device__ inline f32x4 cvt4(u16x4 v) {
  return (f32x4){bf2f(v[0]), bf2f(v[1]), bf2f(v[2]), bf2f(v[3])};
}

// ---------------- build phase 1: deg count + coarse bucket scatter ----------------

__global__ __launch_bounds__(256) void build1_kernel(const int* __restrict__ edges,
                                                     int* __restrict__ deg,
                                                     int* __restrict__ bcur,
                                                     int2* __restrict__ tmp, int gbase) {
  int gw = blockIdx.y;
  size_t ebase = (size_t)(gbase + gw) * 2 * EE;
  int e = blockIdx.x * 256 + threadIdx.x;         // grid.x*256 == EE exactly
  int src = edges[ebase + e];
  int dst = edges[ebase + EE + e];
  atomicAdd(&deg[gw * NN + dst], 1);
  int b = dst >> 10;
  int pos = atomicAdd(&bcur[gw * NB + b], 1);
  if (pos < CAP)                                   // never trips (fixed inputs); OOB guard
    tmp[((size_t)gw * NB + b) * CAP + pos] = make_int2(src, dst);
}

// ---------------- scan: deg -> row_off (exclusive), dinv, deg := 0 ----------------

__global__ __launch_bounds__(1024) void scan_kernel(int* __restrict__ deg, int* __restrict__ row_off,
                                                    float* __restrict__ dinv) {
  int gw  = blockIdx.x;
  int tid = threadIdx.x;
  int lane = tid & 63, wid = tid >> 6;
  __shared__ int wsum[16];
  __shared__ int carry_s;
  if (tid == 0) carry_s = 0;
  __syncthreads();
  int*   dg = deg + gw * NN;
  int*   ro = row_off + gw * (NN + 1);
  float* dv = dinv + gw * NN;
  for (int base = 0; base < NN; base += 1024) {
    int i = base + tid;
    int v = 0;
    if (i < NN) {
      v = dg[i];
      dv[i] = rsqrtf((float)v + 1.0f);
      dg[i] = 0;                                   // becomes cursor for build2
    }
    int incl = v;
    #pragma unroll
    for (int off = 1; off < 64; off <<= 1) {
      int t = __shfl_up(incl, off);
      if (lane >= off) incl += t;
    }
    if (lane == 63) wsum[wid] = incl;
    __syncthreads();
    if (tid == 0) {
      int s = 0;
      #pragma unroll
      for (int w = 0; w < 16; ++w) { int t = wsum[w]; wsum[w] = s; s += t; }
    }
    __syncthreads();
    int excl = carry_s + wsum[wid] + (incl - v);
    if (i < NN) ro[i] = excl;
    __syncthreads();
    if (tid == 1023) carry_s = excl + v;
    __syncthreads();
  }
  if (tid == 0) ro[NN] = carry_s;
}

// ---------------- build phase 2: bucket -> CSR (writes land in ~64KB L2-hot region) ----

__global__ __launch_bounds__(256) void build2_kernel(const int2* __restrict__ tmp,
                                                     const int* __restrict__ bcur,
                                                     int* __restrict__ cursor,
                                                     const int* __restrict__ row_off,
                                                     int* __restrict__ csr) {
  int gw = blockIdx.y;
  int b = blockIdx.x / PB, part = blockIdx.x % PB;
  int cnt = bcur[gw * NB + b];
  if (cnt > CAP) cnt = CAP;
  const int2* tb = tmp + ((size_t)gw * NB + b) * CAP;
  const int* ro = row_off + gw * (NN + 1);
  int* cur = cursor + gw * NN;
  int* cg  = csr + (size_t)gw * EE;
  for (int e = part * 256 + threadIdx.x; e < cnt; e += 256 * PB) {
    int2 p = tb[e];
    int slot = atomicAdd(&cur[p.y], 1);
    cg[ro[p.y] + slot] = p.x;
  }
}

// ---------------- W^T hi/lo precompute ----------------

__global__ __launch_bounds__(256) void wtprep_kernel(const float* __restrict__ W0,
                                                     const float* __restrict__ W1,
                                                     const float* __restrict__ W2,
                                                     __bf16* __restrict__ wt) {
  const float* Wl[3] = {W0, W1, W2};
  int l = blockIdx.x;
  const float* W = Wl[l];
  __bf16* hi = wt + (size_t)l * 2 * F * F;
  __bf16* lo = hi + F * F;
  for (int idx = threadIdx.x; idx < F * F; idx += 256) {
    int k = idx >> 7, c = idx & 127;
    float f = W[idx];
    __bf16 h = (__bf16)f;
    hi[c * F + k] = h;                  // transposed: [col][k]
    lo[c * F + k] = (__bf16)(f - (float)h);
  }
}

// ---------------- batched hi/lo MFMA GEMM: h1[gw] = (act[g] @ W) * dinv[row] (bf16) ----
// 1D grid, gw = bid % Cg pins graph -> XCD (round-robin heuristic).

__global__ __launch_bounds__(256) void gemm_kernel(const float* __restrict__ act,
                                                   const __bf16* __restrict__ wt,
                                                   const float* __restrict__ dinv,
                                                   unsigned short* __restrict__ h1,
                                                   int gbase, int Cg) {
  __shared__ float As[64][132];   // reused as u16 [64][136] staging after MFMA
  int bid = blockIdx.x;
  int gw = bid % Cg, xb = bid / Cg;
  const float* hg = act + (size_t)(gbase + gw) * NN * F;
  unsigned short* h1g = h1 + (size_t)gw * NN * F;
  const float* dv = dinv + (size_t)gw * NN;
  int t = threadIdx.x;
  int row0 = xb * 64;

  int lane4 = t & 31, r8 = t >> 5;
  #pragma unroll
  for (int i = 0; i < 8; ++i) {
    int r = r8 * 8 + i;
    int grow = row0 + r;
    float4_t v = {0.f, 0.f, 0.f, 0.f};
    if (grow < NN) v = *(const float4_t*)(hg + (size_t)grow * F + lane4 * 4);
    *(float4_t*)(&As[r][lane4 * 4]) = v;
  }
  __syncthreads();

  int w = t >> 6, l = t & 63;
  int arow = 16 * w + (l & 15);
  int kgrp = (l >> 4) * 8;                    // A & B share the same k-bijection
  bf16x8 ahi[4], alo[4];
  #pragma unroll
  for (int ks = 0; ks < 4; ++ks) {
    #pragma unroll
    for (int j = 0; j < 8; ++j) {
      float f = As[arow][ks * 32 + kgrp + j];
      __bf16 h = (__bf16)f;
      ahi[ks][j] = h;
      alo[ks][j] = (__bf16)(f - (float)h);
    }
  }
  int drow0 = 16 * w + (l >> 4) * 4;          // D: col=lane&15, row=(lane>>4)*4+q (m89)
  float di4[4];
  #pragma unroll
  for (int q = 0; q < 4; ++q) {
    int grow = row0 + drow0 + q;
    di4[q] = (grow < NN) ? dv[grow] : 0.f;
  }
  __syncthreads();                            // all As reads done; reuse as staging
  unsigned short* St = (unsigned short*)&As[0][0];   // [64][136]
  const __bf16* wthi = wt;                    // [128 cols][128 k]
  const __bf16* wtlo = wt + F * F;
  #pragma unroll
  for (int tile = 0; tile < 8; ++tile) {
    f32x4 acc = {0.f, 0.f, 0.f, 0.f};
    int bcol = tile * 16 + (l & 15);
    #pragma unroll
    for (int ks = 0; ks < 4; ++ks) {
      bf16x8 bhi = *(const bf16x8*)(wthi + (size_t)bcol * F + ks * 32 + kgrp);
      bf16x8 blo = *(const bf16x8*)(wtlo + (size_t)bcol * F + ks * 32 + kgrp);
      acc = __builtin_amdgcn_mfma_f32_16x16x32_bf16(ahi[ks], bhi, acc, 0, 0, 0);
      acc = __builtin_amdgcn_mfma_f32_16x16x32_bf16(ahi[ks], blo, acc, 0, 0, 0);
      acc = __builtin_amdgcn_mfma_f32_16x16x32_bf16(alo[ks], bhi, acc, 0, 0, 0);
    }
    #pragma unroll
    for (int q = 0; q < 4; ++q)
      St[(drow0 + q) * 136 + bcol] = f2bf(acc[q] * di4[q]);
  }
  __syncthreads();
  #pragma unroll
  for (int p = 0; p < 4; ++p) {               // coalesced copy-out: 16KB, 16B/thread/iter
    int idx = p * 256 + t;
    int r = idx >> 4, c = (idx & 15) * 8;
    int grow = row0 + r;
    if (grow < NN)
      *(u16x8*)(h1g + (size_t)grow * F + c) = *(const u16x8*)(&St[r * 136 + c]);
  }
}

// ---------------- batched aggregation: out[g] = relu(dinv*(self+gather) + b) ----
// h1 rows pre-scaled by dinv[src]; 32 lanes/node, ILP-4; 1D grid XCD-pinned.

__global__ __launch_bounds__(256) void agg_kernel(const unsigned short* __restrict__ h1,
                                                  const int* __restrict__ csr,
                                                  const int* __restrict__ row_off,
                                                  const float* __restrict__ dinv,
                                                  const float* __restrict__ bias,
                                                  float* __restrict__ out, int gbase, int Cg) {
  int bid = blockIdx.x;
  int gw = bid % Cg, xb = bid / Cg;
  const unsigned short* hg = h1 + (size_t)gw * NN * F;
  const int*   cs = csr + (size_t)gw * EE;
  const int*   ro = row_off + gw * (NN + 1);
  const float* dv = dinv + (size_t)gw * NN;
  float* outg = out + (size_t)(gbase + gw) * NN * F;

  int grp = threadIdx.x >> 5, lane = threadIdx.x & 31;
  int node = xb * 8 + grp;
  if (node >= NN) return;
  int e0 = ro[node], e1 = ro[node + 1];
  float di = dv[node];
  f32x4 acc0 = cvt4(*(const u16x4*)(hg + (size_t)node * F + lane * 4));  // self (scaled)
  f32x4 acc1 = {0.f, 0.f, 0.f, 0.f};
  f32x4 acc2 = {0.f, 0.f, 0.f, 0.f};
  f32x4 acc3 = {0.f, 0.f, 0.f, 0.f};
  int e = e0;
  for (; e + 3 < e1; e += 4) {
    int s0 = cs[e], s1 = cs[e + 1], s2 = cs[e + 2], s3 = cs[e + 3];
    u16x4 v0 = *(const u16x4*)(hg + (size_t)s0 * F + lane * 4);
    u16x4 v1 = *(const u16x4*)(hg + (size_t)s1 * F + lane * 4);
    u16x4 v2 = *(const u16x4*)(hg + (size_t)s2 * F + lane * 4);
    u16x4 v3 = *(const u16x4*)(hg + (size_t)s3 * F + lane * 4);
    acc0 += cvt4(v0);
    acc1 += cvt4(v1);
    acc2 += cvt4(v2);
    acc3 += cvt4(v3);
  }
  for (; e < e1; ++e) {
    int s = cs[e];
    acc0 += cvt4(*(const u16x4*)(hg + (size_t)s * F + lane * 4));
  }
  f32x4 acc = (acc0 + acc1) + (acc2 + acc3);
  float4_t bb = *(const float4_t*)(bias + lane * 4);
  float4_t o;
  #pragma unroll
  for (int j = 0; j < 4; ++j) o[j] = fmaxf(fmaf(acc[j], di, bb[j]), 0.f);
  *(float4_t*)(outg + (size_t)node * F + lane * 4) = o;
}

// ---------------- host launch ----------------

extern "C" void kernel_launch(void* const* d_in, const int* in_sizes, int n_in,
                              void* d_out, int out_size, void* d_ws, size_t ws_size,
                              hipStream_t stream) {
  const float* x     = (const float*)d_in[0];
  const int*   edges = (const int*)d_in[1];
  const float* Ws[3] = {(const float*)d_in[2], (const float*)d_in[4], (const float*)d_in[6]};
  const float* bs[3] = {(const float*)d_in[3], (const float*)d_in[5], (const float*)d_in[7]};
  float* out = (float*)d_out;

  size_t sz_h1   = (size_t)NN * F * 2;            // 12.8 MB bf16 per graph
  size_t sz_wt   = (size_t)3 * 2 * F * F * 2;     // 196608 B
  size_t sz_csr  = (size_t)EE * 4;                // 3.2 MB
  size_t sz_deg  = (size_t)NN * 4;
  size_t sz_bcur = (size_t)NB * 4;
  size_t sz_dv   = (size_t)NN * 4;
  size_t sz_ro   = (size_t)(NN + 1) * 4;
  size_t sz_tmp  = (size_t)NB * CAP * 8;          // 7.2 MB
  size_t per_g   = sz_h1 + sz_csr + sz_deg + sz_bcur + sz_dv + sz_ro + sz_tmp;  // ~23.9 MB

  int CB = (int)((ws_size > sz_wt ? ws_size - sz_wt : 0) / per_g);
  if (CB < 1) CB = 1;
  if (CB > G) CB = G;

  char* p = (char*)d_ws;
  unsigned short* h1      = (unsigned short*)p;  p += sz_h1 * CB;
  __bf16*         wt      = (__bf16*)p;          p += sz_wt;
  int*            csr     = (int*)p;             p += sz_csr * CB;
  int*            deg     = (int*)p;             p += sz_deg * CB;   // doubles as cursor
  int*            bcur    = (int*)p;             p += sz_bcur * CB;  // adjacent to deg: one memset
  float*          dinv    = (float*)p;           p += sz_dv  * CB;
  int2*           tmp     = (int2*)p;            p += sz_tmp * CB;
  int*            row_off = (int*)p;

  wtprep_kernel<<<3, 256, 0, stream>>>(Ws[0], Ws[1], Ws[2], wt);

  int nblk_g = (NN + 63) / 64;   // 782
  int nblk_a = (NN + 7) / 8;     // 6250

  for (int gb = 0; gb < G; gb += CB) {
    int Cg = G - gb < CB ? G - gb : CB;
    hipMemsetAsync(deg, 0, (sz_deg + sz_bcur) * CB, stream);
    build1_kernel<<<dim3(EE / 256, Cg), 256, 0, stream>>>(edges, deg, bcur, tmp, gb);
    scan_kernel  <<<Cg, 1024, 0, stream>>>(deg, row_off, dinv);
    build2_kernel<<<dim3(NB * PB, Cg), 256, 0, stream>>>(tmp, bcur, deg, row_off, csr);
    for (int l = 0; l < 3; ++l) {
      const float* act = (l == 0) ? x : (const float*)out;
      gemm_kernel<<<nblk_g * Cg, 256, 0, stream>>>(act, wt + (size_t)l * 2 * F * F,
                                                   dinv, h1, gb, Cg);
      agg_kernel <<<nblk_a * Cg, 256, 0, stream>>>(h1, csr, row_off, dinv, bs[l], out, gb, Cg);
    }
  }
}

// Round 7
// 2040.851 us; speedup vs baseline: 4.1390x; 4.1390x over previous
//
#include <hip/hip_runtime.h>

constexpr int G  = 8;
constexpr int NN = 50000;
constexpr int EE = 800000;
constexpr int F  = 128;

typedef float  float4_t __attribute__((ext_vector_type(4)));
typedef float  f32x4    __attribute__((ext_vector_type(4)));
typedef __bf16 bf16x8   __attribute__((ext_vector_type(8)));
typedef unsigned short u16x4 __attribute__((ext_vector_type(4)));
typedef unsigned short u16x8 __attribute__((ext_vector_type(8)));

__device__ inline float bf2f(unsigned short u) {
  union { unsigned int i; float f; } v; v.i = (unsigned int)u << 16; return v.f;
}
__device__ inline unsigned short f2bf(float f) {
  union { __bf16 b; unsigned short u; } v; v.b = (__bf16)f; return v.u;   // RNE
}
__device__ inline f32x4 cvt4(u16x4 v) {
  return (f32x4){bf2f(v[0]), bf2f(v[1]), bf2f(v[2]), bf2f(v[3])};
}

// ---------------- graph structure build ----------------
// 1D grids with gw = bid % Cg: round-robin block->XCD dispatch pins each graph's
// deg/cursor/CSR working set (~3.4MB) inside one XCD's 4MB L2, so scattered 4B
// CSR writes coalesce in-cache instead of evicting partially-filled 64B lines.

__global__ __launch_bounds__(256) void deg_kernel(const int* __restrict__ edges,
                                                  int* __restrict__ deg, int gbase, int Cg) {
  int bid = blockIdx.x;
  int gw = bid % Cg, eb = bid / Cg;
  size_t ebase = ((size_t)(gbase + gw) * 2 + 1) * EE;   // dst half
  int e = eb * 256 + threadIdx.x;                       // (EE/256)*Cg blocks total
  int dst = edges[ebase + e];
  atomicAdd(&deg[gw * NN + dst], 1);
}

__global__ __launch_bounds__(1024) void scan_kernel(int* __restrict__ deg, int* __restrict__ row_off,
                                                    float* __restrict__ dinv) {
  int gw  = blockIdx.x;
  int tid = threadIdx.x;
  int lane = tid & 63, wid = tid >> 6;
  __shared__ int wsum[16];
  __shared__ int carry_s;
  if (tid == 0) carry_s = 0;
  __syncthreads();
  int*   dg = deg + gw * NN;
  int*   ro = row_off + gw * (NN + 1);
  float* dv = dinv + gw * NN;
  for (int base = 0; base < NN; base += 1024) {
    int i = base + tid;
    int v = 0;
    if (i < NN) {
      v = dg[i];
      dv[i] = rsqrtf((float)v + 1.0f);
      dg[i] = 0;                                   // becomes cursor for fill
    }
    int incl = v;
    #pragma unroll
    for (int off = 1; off < 64; off <<= 1) {
      int t = __shfl_up(incl, off);
      if (lane >= off) incl += t;
    }
    if (lane == 63) wsum[wid] = incl;
    __syncthreads();
    if (tid == 0) {
      int s = 0;
      #pragma unroll
      for (int w = 0; w < 16; ++w) { int t = wsum[w]; wsum[w] = s; s += t; }
    }
    __syncthreads();
    int excl = carry_s + wsum[wid] + (incl - v);
    if (i < NN) ro[i] = excl;
    __syncthreads();
    if (tid == 1023) carry_s = excl + v;
    __syncthreads();
  }
  if (tid == 0) ro[NN] = carry_s;
}

__global__ __launch_bounds__(256) void fill_kernel(const int* __restrict__ edges,
                                                   int* __restrict__ cursor, const int* __restrict__ row_off,
                                                   int* __restrict__ csr, int gbase, int Cg) {
  int bid = blockIdx.x;
  int gw = bid % Cg, eb = bid / Cg;
  size_t ebase = (size_t)(gbase + gw) * 2 * EE;
  int e = eb * 256 + threadIdx.x;
  int src = edges[ebase + e];
  int dst = edges[ebase + EE + e];
  int slot = atomicAdd(&cursor[gw * NN + dst], 1);
  csr[(size_t)gw * EE + row_off[gw * (NN + 1) + dst] + slot] = src;
}

// ---------------- W^T hi/lo precompute ----------------

__global__ __launch_bounds__(256) void wtprep_kernel(const float* __restrict__ W0,
                                                     const float* __restrict__ W1,
                                                     const float* __restrict__ W2,
                                                     __bf16* __restrict__ wt) {
  const float* Wl[3] = {W0, W1, W2};
  int l = blockIdx.x;
  const float* W = Wl[l];
  __bf16* hi = wt + (size_t)l * 2 * F * F;
  __bf16* lo = hi + F * F;
  for (int idx = threadIdx.x; idx < F * F; idx += 256) {
    int k = idx >> 7, c = idx & 127;
    float f = W[idx];
    __bf16 h = (__bf16)f;
    hi[c * F + k] = h;                  // transposed: [col][k]
    lo[c * F + k] = (__bf16)(f - (float)h);
  }
}

// ---------------- batched hi/lo MFMA GEMM: h1[gw] = (act[g] @ W) * dinv[row] (bf16) ----

__global__ __launch_bounds__(256) void gemm_kernel(const float* __restrict__ act,
                                                   const __bf16* __restrict__ wt,
                                                   const float* __restrict__ dinv,
                                                   unsigned short* __restrict__ h1,
                                                   int gbase, int Cg) {
  __shared__ float As[64][132];   // reused as u16 [64][136] staging after MFMA
  int bid = blockIdx.x;
  int gw = bid % Cg, xb = bid / Cg;
  const float* hg = act + (size_t)(gbase + gw) * NN * F;
  unsigned short* h1g = h1 + (size_t)gw * NN * F;
  const float* dv = dinv + (size_t)gw * NN;
  int t = threadIdx.x;
  int row0 = xb * 64;

  int lane4 = t & 31, r8 = t >> 5;
  #pragma unroll
  for (int i = 0; i < 8; ++i) {
    int r = r8 * 8 + i;
    int grow = row0 + r;
    float4_t v = {0.f, 0.f, 0.f, 0.f};
    if (grow < NN) v = *(const float4_t*)(hg + (size_t)grow * F + lane4 * 4);
    *(float4_t*)(&As[r][lane4 * 4]) = v;
  }
  __syncthreads();

  int w = t >> 6, l = t & 63;
  int arow = 16 * w + (l & 15);
  int kgrp = (l >> 4) * 8;                    // A & B share the same k-bijection
  bf16x8 ahi[4], alo[4];
  #pragma unroll
  for (int ks = 0; ks < 4; ++ks) {
    #pragma unroll
    for (int j = 0; j < 8; ++j) {
      float f = As[arow][ks * 32 + kgrp + j];
      __bf16 h = (__bf16)f;
      ahi[ks][j] = h;
      alo[ks][j] = (__bf16)(f - (float)h);
    }
  }
  int drow0 = 16 * w + (l >> 4) * 4;          // D: col=lane&15, row=(lane>>4)*4+q (m89)
  float di4[4];
  #pragma unroll
  for (int q = 0; q < 4; ++q) {
    int grow = row0 + drow0 + q;
    di4[q] = (grow < NN) ? dv[grow] : 0.f;
  }
  __syncthreads();                            // all As reads done; reuse as staging
  unsigned short* St = (unsigned short*)&As[0][0];   // [64][136]
  const __bf16* wthi = wt;                    // [128 cols][128 k]
  const __bf16* wtlo = wt + F * F;
  #pragma unroll
  for (int tile = 0; tile < 8; ++tile) {
    f32x4 acc = {0.f, 0.f, 0.f, 0.f};
    int bcol = tile * 16 + (l & 15);
    #pragma unroll
    for (int ks = 0; ks < 4; ++ks) {
      bf16x8 bhi = *(const bf16x8*)(wthi + (size_t)bcol * F + ks * 32 + kgrp);
      bf16x8 blo = *(const bf16x8*)(wtlo + (size_t)bcol * F + ks * 32 + kgrp);
      acc = __builtin_amdgcn_mfma_f32_16x16x32_bf16(ahi[ks], bhi, acc, 0, 0, 0);
      acc = __builtin_amdgcn_mfma_f32_16x16x32_bf16(ahi[ks], blo, acc, 0, 0, 0);
      acc = __builtin_amdgcn_mfma_f32_16x16x32_bf16(alo[ks], bhi, acc, 0, 0, 0);
    }
    #pragma unroll
    for (int q = 0; q < 4; ++q)
      St[(drow0 + q) * 136 + bcol] = f2bf(acc[q] * di4[q]);
  }
  __syncthreads();
  #pragma unroll
  for (int p = 0; p < 4; ++p) {               // coalesced copy-out: 16KB, 16B/thread/iter
    int idx = p * 256 + t;
    int r = idx >> 4, c = (idx & 15) * 8;
    int grow = row0 + r;
    if (grow < NN)
      *(u16x8*)(h1g + (size_t)grow * F + c) = *(const u16x8*)(&St[r * 136 + c]);
  }
}

// ---------------- batched aggregation: out[g] = relu(dinv*(self+gather) + b) ----
// h1 rows pre-scaled by dinv[src]; 32 lanes/node, ILP-4; 1D grid XCD-pinned.

__global__ __launch_bounds__(256) void agg_kernel(const unsigned short* __restrict__ h1,
                                                  const int* __restrict__ csr,
                                                  const int* __restrict__ row_off,
                                                  const float* __restrict__ dinv,
                                                  const float* __restrict__ bias,
                                                  float* __restrict__ out, int gbase, int Cg) {
  int bid = blockIdx.x;
  int gw = bid % Cg, xb = bid / Cg;
  const unsigned short* hg = h1 + (size_t)gw * NN * F;
  const int*   cs = csr + (size_t)gw * EE;
  const int*   ro = row_off + gw * (NN + 1);
  const float* dv = dinv + (size_t)gw * NN;
  float* outg = out + (size_t)(gbase + gw) * NN * F;

  int grp = threadIdx.x >> 5, lane = threadIdx.x & 31;
  int node = xb * 8 + grp;
  if (node >= NN) return;
  int e0 = ro[node], e1 = ro[node + 1];
  float di = dv[node];
  f32x4 acc0 = cvt4(*(const u16x4*)(hg + (size_t)node * F + lane * 4));  // self (scaled)
  f32x4 acc1 = {0.f, 0.f, 0.f, 0.f};
  f32x4 acc2 = {0.f, 0.f, 0.f, 0.f};
  f32x4 acc3 = {0.f, 0.f, 0.f, 0.f};
  int e = e0;
  for (; e + 3 < e1; e += 4) {
    int s0 = cs[e], s1 = cs[e + 1], s2 = cs[e + 2], s3 = cs[e + 3];
    u16x4 v0 = *(const u16x4*)(hg + (size_t)s0 * F + lane * 4);
    u16x4 v1 = *(const u16x4*)(hg + (size_t)s1 * F + lane * 4);
    u16x4 v2 = *(const u16x4*)(hg + (size_t)s2 * F + lane * 4);
    u16x4 v3 = *(const u16x4*)(hg + (size_t)s3 * F + lane * 4);
    acc0 += cvt4(v0);
    acc1 += cvt4(v1);
    acc2 += cvt4(v2);
    acc3 += cvt4(v3);
  }
  for (; e < e1; ++e) {
    int s = cs[e];
    acc0 += cvt4(*(const u16x4*)(hg + (size_t)s * F + lane * 4));
  }
  f32x4 acc = (acc0 + acc1) + (acc2 + acc3);
  float4_t bb = *(const float4_t*)(bias + lane * 4);
  float4_t o;
  #pragma unroll
  for (int j = 0; j < 4; ++j) o[j] = fmaxf(fmaf(acc[j], di, bb[j]), 0.f);
  *(float4_t*)(outg + (size_t)node * F + lane * 4) = o;
}

// ---------------- host launch ----------------

extern "C" void kernel_launch(void* const* d_in, const int* in_sizes, int n_in,
                              void* d_out, int out_size, void* d_ws, size_t ws_size,
                              hipStream_t stream) {
  const float* x     = (const float*)d_in[0];
  const int*   edges = (const int*)d_in[1];
  const float* Ws[3] = {(const float*)d_in[2], (const float*)d_in[4], (const float*)d_in[6]};
  const float* bs[3] = {(const float*)d_in[3], (const float*)d_in[5], (const float*)d_in[7]};
  float* out = (float*)d_out;

  size_t sz_h1  = (size_t)NN * F * 2;           // 12.8 MB bf16 per graph
  size_t sz_wt  = (size_t)3 * 2 * F * F * 2;    // 196608 B
  size_t sz_csr = (size_t)EE * 4;
  size_t sz_deg = (size_t)NN * 4;
  size_t sz_dv  = (size_t)NN * 4;
  size_t sz_ro  = (size_t)(NN + 1) * 4;
  size_t per_g  = sz_h1 + sz_csr + sz_deg + sz_dv + sz_ro;  // ~16.5 MB

  int CB = (int)((ws_size > sz_wt ? ws_size - sz_wt : 0) / per_g);
  if (CB < 1) CB = 1;
  if (CB > G) CB = G;

  char* p = (char*)d_ws;
  unsigned short* h1      = (unsigned short*)p;  p += sz_h1 * CB;
  __bf16*         wt      = (__bf16*)p;          p += sz_wt;
  int*            csr     = (int*)p;             p += sz_csr * CB;
  int*            deg     = (int*)p;             p += sz_deg * CB;   // doubles as cursor
  float*          dinv    = (float*)p;           p += sz_dv  * CB;
  int*            row_off = (int*)p;

  wtprep_kernel<<<3, 256, 0, stream>>>(Ws[0], Ws[1], Ws[2], wt);

  int nblk_e = EE / 256;         // 3125
  int nblk_g = (NN + 63) / 64;   // 782
  int nblk_a = (NN + 7) / 8;     // 6250

  for (int gb = 0; gb < G; gb += CB) {
    int Cg = G - gb < CB ? G - gb : CB;
    hipMemsetAsync(deg, 0, sz_deg * CB, stream);
    deg_kernel <<<nblk_e * Cg, 256, 0, stream>>>(edges, deg, gb, Cg);
    scan_kernel<<<Cg, 1024, 0, stream>>>(deg, row_off, dinv);
    fill_kernel<<<nblk_e * Cg, 256, 0, stream>>>(edges, deg, row_off, csr, gb, Cg);
    for (int l = 0; l < 3; ++l) {
      const float* act = (l == 0) ? x : (const float*)out;
      gemm_kernel<<<nblk_g * Cg, 256, 0, stream>>>(act, wt + (size_t)l * 2 * F * F,
                                                   dinv, h1, gb, Cg);
      agg_kernel <<<nblk_a * Cg, 256, 0, stream>>>(h1, csr, row_off, dinv, bs[l], out, gb, Cg);
    }
  }
}

// Round 8
// 1792.388 us; speedup vs baseline: 4.7127x; 1.1386x over previous
//
#include <hip/hip_runtime.h>

constexpr int G  = 8;
constexpr int NN = 50000;
constexpr int EE = 800000;
constexpr int F  = 128;

typedef float  float4_t __attribute__((ext_vector_type(4)));
typedef float  f32x4    __attribute__((ext_vector_type(4)));
typedef __bf16 bf16x8   __attribute__((ext_vector_type(8)));
typedef unsigned short u16x8 __attribute__((ext_vector_type(8)));

__device__ inline float bf2f(unsigned short u) {
  union { unsigned int i; float f; } v; v.i = (unsigned int)u << 16; return v.f;
}
__device__ inline unsigned short f2bf(float f) {
  union { __bf16 b; unsigned short u; } v; v.b = (__bf16)f; return v.u;   // RNE
}
__device__ inline void addrow(f32x4& a, f32x4& b, u16x8 v) {
  a += (f32x4){bf2f(v[0]), bf2f(v[1]), bf2f(v[2]), bf2f(v[3])};
  b += (f32x4){bf2f(v[4]), bf2f(v[5]), bf2f(v[6]), bf2f(v[7])};
}

// ---------------- graph structure build ----------------
// edge_index int32, [G,2,E]. CSR stored u16 (src<50000<65536).
// Cursor is initialized to row starts by scan, so fill's atomicAdd yields the
// absolute CSR slot (no row_off read in the hot scatter loop).

__global__ __launch_bounds__(256) void deg_kernel(const int* __restrict__ edges,
                                                  int* __restrict__ deg, int gbase, int Cg) {
  int bid = blockIdx.x;
  int gw = bid % Cg, eb = bid / Cg;
  size_t ebase = ((size_t)(gbase + gw) * 2 + 1) * EE;   // dst half
  int e = eb * 256 + threadIdx.x;                       // (EE/256)*Cg blocks
  int dst = edges[ebase + e];
  atomicAdd(&deg[gw * NN + dst], 1);
}

// exclusive scan of deg -> row_off AND cursor(=row start); dinv = rsqrt(deg+1)
__global__ __launch_bounds__(1024) void scan_kernel(int* __restrict__ deg, int* __restrict__ row_off,
                                                    float* __restrict__ dinv) {
  int gw  = blockIdx.x;
  int tid = threadIdx.x;
  int lane = tid & 63, wid = tid >> 6;
  __shared__ int wsum[16];
  __shared__ int carry_s;
  if (tid == 0) carry_s = 0;
  __syncthreads();
  int*   dg = deg + gw * NN;          // in: counts, out: cursor (row starts)
  int*   ro = row_off + gw * (NN + 1);
  float* dv = dinv + gw * NN;
  for (int base = 0; base < NN; base += 1024) {
    int i = base + tid;
    int v = 0;
    if (i < NN) {
      v = dg[i];
      dv[i] = rsqrtf((float)v + 1.0f);
    }
    int incl = v;
    #pragma unroll
    for (int off = 1; off < 64; off <<= 1) {
      int t = __shfl_up(incl, off);
      if (lane >= off) incl += t;
    }
    if (lane == 63) wsum[wid] = incl;
    __syncthreads();
    if (tid == 0) {
      int s = 0;
      #pragma unroll
      for (int w = 0; w < 16; ++w) { int t = wsum[w]; wsum[w] = s; s += t; }
    }
    __syncthreads();
    int excl = carry_s + wsum[wid] + (incl - v);
    if (i < NN) { ro[i] = excl; dg[i] = excl; }
    __syncthreads();
    if (tid == 1023) carry_s = excl + v;
    __syncthreads();
  }
  if (tid == 0) ro[NN] = carry_s;          // == EE
}

__global__ __launch_bounds__(256) void fill_kernel(const int* __restrict__ edges,
                                                   int* __restrict__ cursor,
                                                   unsigned short* __restrict__ csr,
                                                   int gbase, int Cg) {
  int bid = blockIdx.x;
  int gw = bid % Cg, eb = bid / Cg;
  size_t ebase = (size_t)(gbase + gw) * 2 * EE;
  int e = eb * 256 + threadIdx.x;
  int src = edges[ebase + e];
  int dst = edges[ebase + EE + e];
  int pos = atomicAdd(&cursor[gw * NN + dst], 1);   // absolute slot
  csr[(size_t)gw * EE + pos] = (unsigned short)src;
}

// ---------------- W^T hi/lo precompute ----------------

__global__ __launch_bounds__(256) void wtprep_kernel(const float* __restrict__ W0,
                                                     const float* __restrict__ W1,
                                                     const float* __restrict__ W2,
                                                     __bf16* __restrict__ wt) {
  const float* Wl[3] = {W0, W1, W2};
  int l = blockIdx.x;
  const float* W = Wl[l];
  __bf16* hi = wt + (size_t)l * 2 * F * F;
  __bf16* lo = hi + F * F;
  for (int idx = threadIdx.x; idx < F * F; idx += 256) {
    int k = idx >> 7, c = idx & 127;
    float f = W[idx];
    __bf16 h = (__bf16)f;
    hi[c * F + k] = h;                  // transposed: [col][k]
    lo[c * F + k] = (__bf16)(f - (float)h);
  }
}

// ---------------- GEMM A: layer-0 (f32 x input), hi/lo A split, 3 MFMA terms ----

__global__ __launch_bounds__(256) void gemm0_kernel(const float* __restrict__ act,
                                                    const __bf16* __restrict__ wt,
                                                    const float* __restrict__ dinv,
                                                    unsigned short* __restrict__ h1,
                                                    int gbase, int Cg) {
  __shared__ float As[64][132];   // reused as u16 [64][136] staging after MFMA
  int bid = blockIdx.x;
  int gw = bid % Cg, xb = bid / Cg;
  const float* hg = act + (size_t)(gbase + gw) * NN * F;
  unsigned short* h1g = h1 + (size_t)gw * NN * F;
  const float* dv = dinv + (size_t)gw * NN;
  int t = threadIdx.x;
  int row0 = xb * 64;

  int lane4 = t & 31, r8 = t >> 5;
  #pragma unroll
  for (int i = 0; i < 8; ++i) {
    int r = r8 * 8 + i;
    int grow = row0 + r;
    float4_t v = {0.f, 0.f, 0.f, 0.f};
    if (grow < NN) v = *(const float4_t*)(hg + (size_t)grow * F + lane4 * 4);
    *(float4_t*)(&As[r][lane4 * 4]) = v;
  }
  __syncthreads();

  int w = t >> 6, l = t & 63;
  int arow = 16 * w + (l & 15);
  int kgrp = (l >> 4) * 8;                    // A & B share the same k-bijection
  bf16x8 ahi[4], alo[4];
  #pragma unroll
  for (int ks = 0; ks < 4; ++ks) {
    #pragma unroll
    for (int j = 0; j < 8; ++j) {
      float f = As[arow][ks * 32 + kgrp + j];
      __bf16 h = (__bf16)f;
      ahi[ks][j] = h;
      alo[ks][j] = (__bf16)(f - (float)h);
    }
  }
  int drow0 = 16 * w + (l >> 4) * 4;          // D: col=lane&15, row=(lane>>4)*4+q (m89)
  float di4[4];
  #pragma unroll
  for (int q = 0; q < 4; ++q) {
    int grow = row0 + drow0 + q;
    di4[q] = (grow < NN) ? dv[grow] : 0.f;
  }
  __syncthreads();                            // reuse As as bf16 staging
  unsigned short* St = (unsigned short*)&As[0][0];   // [64][136]
  const __bf16* wthi = wt;
  const __bf16* wtlo = wt + F * F;
  #pragma unroll
  for (int tile = 0; tile < 8; ++tile) {
    f32x4 acc = {0.f, 0.f, 0.f, 0.f};
    int bcol = tile * 16 + (l & 15);
    #pragma unroll
    for (int ks = 0; ks < 4; ++ks) {
      bf16x8 bhi = *(const bf16x8*)(wthi + (size_t)bcol * F + ks * 32 + kgrp);
      bf16x8 blo = *(const bf16x8*)(wtlo + (size_t)bcol * F + ks * 32 + kgrp);
      acc = __builtin_amdgcn_mfma_f32_16x16x32_bf16(ahi[ks], bhi, acc, 0, 0, 0);
      acc = __builtin_amdgcn_mfma_f32_16x16x32_bf16(ahi[ks], blo, acc, 0, 0, 0);
      acc = __builtin_amdgcn_mfma_f32_16x16x32_bf16(alo[ks], bhi, acc, 0, 0, 0);
    }
    #pragma unroll
    for (int q = 0; q < 4; ++q)
      St[(drow0 + q) * 136 + bcol] = f2bf(acc[q] * di4[q]);
  }
  __syncthreads();
  #pragma unroll
  for (int p = 0; p < 4; ++p) {               // coalesced copy-out, 16B/thread/iter
    int idx = p * 256 + t;
    int r = idx >> 4, c = (idx & 15) * 8;
    int grow = row0 + r;
    if (grow < NN)
      *(u16x8*)(h1g + (size_t)grow * F + c) = *(const u16x8*)(&St[r * 136 + c]);
  }
}

// ---------------- GEMM B: layers 1,2 (bf16 activations), exact A, 2 MFMA terms ----

__global__ __launch_bounds__(256) void gemmb_kernel(const unsigned short* __restrict__ actb,
                                                    const __bf16* __restrict__ wt,
                                                    const float* __restrict__ dinv,
                                                    unsigned short* __restrict__ h1,
                                                    int Cg) {
  __shared__ unsigned short As[64][136];      // 17.4KB; also output staging
  int bid = blockIdx.x;
  int gw = bid % Cg, xb = bid / Cg;
  const unsigned short* ag = actb + (size_t)gw * NN * F;
  unsigned short* h1g = h1 + (size_t)gw * NN * F;
  const float* dv = dinv + (size_t)gw * NN;
  int t = threadIdx.x;
  int row0 = xb * 64;

  #pragma unroll
  for (int p = 0; p < 4; ++p) {               // stage 64x128 bf16, coalesced 16B
    int idx = p * 256 + t;
    int r = idx >> 4, c = (idx & 15) * 8;
    int grow = row0 + r;
    u16x8 v = (u16x8){0, 0, 0, 0, 0, 0, 0, 0};
    if (grow < NN) v = *(const u16x8*)(ag + (size_t)grow * F + c);
    *(u16x8*)(&As[r][c]) = v;
  }
  __syncthreads();

  int w = t >> 6, l = t & 63;
  int arow = 16 * w + (l & 15);
  int kgrp = (l >> 4) * 8;
  bf16x8 a[4];
  #pragma unroll
  for (int ks = 0; ks < 4; ++ks)
    a[ks] = *(const bf16x8*)((const __bf16*)&As[arow][ks * 32 + kgrp]);
  int drow0 = 16 * w + (l >> 4) * 4;
  float di4[4];
  #pragma unroll
  for (int q = 0; q < 4; ++q) {
    int grow = row0 + drow0 + q;
    di4[q] = (grow < NN) ? dv[grow] : 0.f;
  }
  __syncthreads();                            // reuse As as staging
  const __bf16* wthi = wt;
  const __bf16* wtlo = wt + F * F;
  #pragma unroll
  for (int tile = 0; tile < 8; ++tile) {
    f32x4 acc = {0.f, 0.f, 0.f, 0.f};
    int bcol = tile * 16 + (l & 15);
    #pragma unroll
    for (int ks = 0; ks < 4; ++ks) {
      bf16x8 bhi = *(const bf16x8*)(wthi + (size_t)bcol * F + ks * 32 + kgrp);
      bf16x8 blo = *(const bf16x8*)(wtlo + (size_t)bcol * F + ks * 32 + kgrp);
      acc = __builtin_amdgcn_mfma_f32_16x16x32_bf16(a[ks], bhi, acc, 0, 0, 0);
      acc = __builtin_amdgcn_mfma_f32_16x16x32_bf16(a[ks], blo, acc, 0, 0, 0);
    }
    #pragma unroll
    for (int q = 0; q < 4; ++q)
      As[drow0 + q][bcol] = f2bf(acc[q] * di4[q]);
  }
  __syncthreads();
  #pragma unroll
  for (int p = 0; p < 4; ++p) {
    int idx = p * 256 + t;
    int r = idx >> 4, c = (idx & 15) * 8;
    int grow = row0 + r;
    if (grow < NN)
      *(u16x8*)(h1g + (size_t)grow * F + c) = *(const u16x8*)(&As[r][c]);
  }
}

// ---------------- aggregation: 16 lanes/node, u16x8 gathers, ILP-4 ----------------
// FIN=0: store bf16 into actb (chunk-local). FIN=1: store f32 into d_out (global g).

template<int FIN>
__global__ __launch_bounds__(256) void agg_kernel(const unsigned short* __restrict__ h1,
                                                  const unsigned short* __restrict__ csr,
                                                  const int* __restrict__ row_off,
                                                  const float* __restrict__ dinv,
                                                  const float* __restrict__ bias,
                                                  void* __restrict__ outp, int gbase, int Cg) {
  int bid = blockIdx.x;
  int gw = bid % Cg, xb = bid / Cg;
  const unsigned short* hg = h1 + (size_t)gw * NN * F;
  const unsigned short* cs = csr + (size_t)gw * EE;
  const int*   ro = row_off + gw * (NN + 1);
  const float* dv = dinv + (size_t)gw * NN;

  int grp = threadIdx.x >> 4, lane = threadIdx.x & 15;
  int node = xb * 16 + grp;                   // 3125*16 == 50000 exact
  int e0 = ro[node], e1 = ro[node + 1];
  float di = dv[node];
  f32x4 a0 = {0.f, 0.f, 0.f, 0.f}, b0 = a0, a1 = a0, b1 = a0;
  addrow(a0, b0, *(const u16x8*)(hg + (size_t)node * F + lane * 8));   // self (scaled)
  int e = e0;
  for (; e + 3 < e1; e += 4) {
    int s0 = cs[e], s1 = cs[e + 1], s2 = cs[e + 2], s3 = cs[e + 3];
    u16x8 v0 = *(const u16x8*)(hg + (size_t)s0 * F + lane * 8);
    u16x8 v1 = *(const u16x8*)(hg + (size_t)s1 * F + lane * 8);
    u16x8 v2 = *(const u16x8*)(hg + (size_t)s2 * F + lane * 8);
    u16x8 v3 = *(const u16x8*)(hg + (size_t)s3 * F + lane * 8);
    addrow(a0, b0, v0);
    addrow(a1, b1, v1);
    addrow(a0, b0, v2);
    addrow(a1, b1, v3);
  }
  for (; e < e1; ++e) {
    int s = cs[e];
    addrow(a0, b0, *(const u16x8*)(hg + (size_t)s * F + lane * 8));
  }
  f32x4 ra = a0 + a1, rb = b0 + b1;
  float4_t bb0 = *(const float4_t*)(bias + lane * 8);
  float4_t bb1 = *(const float4_t*)(bias + lane * 8 + 4);
  #pragma unroll
  for (int j = 0; j < 4; ++j) {
    ra[j] = fmaxf(fmaf(ra[j], di, bb0[j]), 0.f);
    rb[j] = fmaxf(fmaf(rb[j], di, bb1[j]), 0.f);
  }
  if (FIN) {
    float* og = (float*)outp + (size_t)(gbase + gw) * NN * F + (size_t)node * F + lane * 8;
    *(float4_t*)og = ra;
    *(float4_t*)(og + 4) = rb;
  } else {
    u16x8 o;
    #pragma unroll
    for (int j = 0; j < 4; ++j) { o[j] = f2bf(ra[j]); o[j + 4] = f2bf(rb[j]); }
    unsigned short* og = (unsigned short*)outp + (size_t)gw * NN * F + (size_t)node * F + lane * 8;
    *(u16x8*)og = o;
  }
}

// ---------------- host launch ----------------

extern "C" void kernel_launch(void* const* d_in, const int* in_sizes, int n_in,
                              void* d_out, int out_size, void* d_ws, size_t ws_size,
                              hipStream_t stream) {
  const float* x     = (const float*)d_in[0];
  const int*   edges = (const int*)d_in[1];
  const float* Ws[3] = {(const float*)d_in[2], (const float*)d_in[4], (const float*)d_in[6]};
  const float* bs[3] = {(const float*)d_in[3], (const float*)d_in[5], (const float*)d_in[7]};
  float* out = (float*)d_out;

  size_t sz_h1  = (size_t)NN * F * 2;           // 12.8 MB bf16 per graph (x2 buffers)
  size_t sz_wt  = (size_t)3 * 2 * F * F * 2;
  size_t sz_csr = (size_t)EE * 2;               // u16 CSR: 1.6 MB per graph
  size_t sz_deg = (size_t)NN * 4;
  size_t sz_dv  = (size_t)NN * 4;
  size_t sz_ro  = (size_t)(NN + 1) * 4;
  size_t per_g  = 2 * sz_h1 + sz_csr + sz_deg + sz_dv + sz_ro;  // ~27.8 MB

  int CB = (int)((ws_size > sz_wt ? ws_size - sz_wt : 0) / per_g);
  if (CB < 1) CB = 1;
  if (CB > G) CB = G;

  char* p = (char*)d_ws;
  unsigned short* h1      = (unsigned short*)p;  p += sz_h1 * CB;
  unsigned short* actb    = (unsigned short*)p;  p += sz_h1 * CB;
  __bf16*         wt      = (__bf16*)p;          p += sz_wt;
  unsigned short* csr     = (unsigned short*)p;  p += sz_csr * CB;
  int*            deg     = (int*)p;             p += sz_deg * CB;   // -> cursor after scan
  float*          dinv    = (float*)p;           p += sz_dv  * CB;
  int*            row_off = (int*)p;

  wtprep_kernel<<<3, 256, 0, stream>>>(Ws[0], Ws[1], Ws[2], wt);

  int nblk_e = EE / 256;         // 3125
  int nblk_g = (NN + 63) / 64;   // 782
  int nblk_a = NN / 16;          // 3125

  for (int gb = 0; gb < G; gb += CB) {
    int Cg = G - gb < CB ? G - gb : CB;
    hipMemsetAsync(deg, 0, sz_deg * CB, stream);
    deg_kernel <<<nblk_e * Cg, 256, 0, stream>>>(edges, deg, gb, Cg);
    scan_kernel<<<Cg, 1024, 0, stream>>>(deg, row_off, dinv);
    fill_kernel<<<nblk_e * Cg, 256, 0, stream>>>(edges, deg, csr, gb, Cg);

    // layer 0
    gemm0_kernel<<<nblk_g * Cg, 256, 0, stream>>>(x, wt, dinv, h1, gb, Cg);
    agg_kernel<0><<<nblk_a * Cg, 256, 0, stream>>>(h1, csr, row_off, dinv, bs[0], actb, gb, Cg);
    // layer 1
    gemmb_kernel<<<nblk_g * Cg, 256, 0, stream>>>(actb, wt + 2 * F * F, dinv, h1, Cg);
    agg_kernel<0><<<nblk_a * Cg, 256, 0, stream>>>(h1, csr, row_off, dinv, bs[1], actb, gb, Cg);
    // layer 2
    gemmb_kernel<<<nblk_g * Cg, 256, 0, stream>>>(actb, wt + 4 * F * F, dinv, h1, Cg);
    agg_kernel<1><<<nblk_a * Cg, 256, 0, stream>>>(h1, csr, row_off, dinv, bs[2], out, gb, Cg);
  }
}

// Round 9
// 1428.462 us; speedup vs baseline: 5.9134x; 1.2548x over previous
//
#include <hip/hip_runtime.h>

constexpr int G  = 8;
constexpr int NN = 50000;
constexpr int EE = 800000;
constexpr int F  = 128;

typedef float  float4_t __attribute__((ext_vector_type(4)));
typedef float  f32x4    __attribute__((ext_vector_type(4)));
typedef __bf16 bf16x8   __attribute__((ext_vector_type(8)));
typedef unsigned short u16x4 __attribute__((ext_vector_type(4)));
typedef unsigned short u16x8 __attribute__((ext_vector_type(8)));

__device__ inline float bf2f(unsigned short u) {
  union { unsigned int i; float f; } v; v.i = (unsigned int)u << 16; return v.f;
}
__device__ inline unsigned short f2bf(float f) {
  union { __bf16 b; unsigned short u; } v; v.b = (__bf16)f; return v.u;   // RNE
}
__device__ inline void addrow(f32x4& a, f32x4& b, u16x8 v) {
  a += (f32x4){bf2f(v[0]), bf2f(v[1]), bf2f(v[2]), bf2f(v[3])};
  b += (f32x4){bf2f(v[4]), bf2f(v[5]), bf2f(v[6]), bf2f(v[7])};
}

// ---------------- graph structure build (unchanged from r8) ----------------

__global__ __launch_bounds__(256) void deg_kernel(const int* __restrict__ edges,
                                                  int* __restrict__ deg, int gbase, int Cg) {
  int bid = blockIdx.x;
  int gw = bid % Cg, eb = bid / Cg;
  size_t ebase = ((size_t)(gbase + gw) * 2 + 1) * EE;   // dst half
  int e = eb * 256 + threadIdx.x;
  int dst = edges[ebase + e];
  atomicAdd(&deg[gw * NN + dst], 1);
}

// exclusive scan of deg -> row_off AND cursor(=row start); dinv = rsqrt(deg+1)
__global__ __launch_bounds__(1024) void scan_kernel(int* __restrict__ deg, int* __restrict__ row_off,
                                                    float* __restrict__ dinv) {
  int gw  = blockIdx.x;
  int tid = threadIdx.x;
  int lane = tid & 63, wid = tid >> 6;
  __shared__ int wsum[16];
  __shared__ int carry_s;
  if (tid == 0) carry_s = 0;
  __syncthreads();
  int*   dg = deg + gw * NN;          // in: counts, out: cursor (row starts)
  int*   ro = row_off + gw * (NN + 1);
  float* dv = dinv + gw * NN;
  for (int base = 0; base < NN; base += 1024) {
    int i = base + tid;
    int v = 0;
    if (i < NN) {
      v = dg[i];
      dv[i] = rsqrtf((float)v + 1.0f);
    }
    int incl = v;
    #pragma unroll
    for (int off = 1; off < 64; off <<= 1) {
      int t = __shfl_up(incl, off);
      if (lane >= off) incl += t;
    }
    if (lane == 63) wsum[wid] = incl;
    __syncthreads();
    if (tid == 0) {
      int s = 0;
      #pragma unroll
      for (int w = 0; w < 16; ++w) { int t = wsum[w]; wsum[w] = s; s += t; }
    }
    __syncthreads();
    int excl = carry_s + wsum[wid] + (incl - v);
    if (i < NN) { ro[i] = excl; dg[i] = excl; }
    __syncthreads();
    if (tid == 1023) carry_s = excl + v;
    __syncthreads();
  }
  if (tid == 0) ro[NN] = carry_s;          // == EE
}

__global__ __launch_bounds__(256) void fill_kernel(const int* __restrict__ edges,
                                                   int* __restrict__ cursor,
                                                   unsigned short* __restrict__ csr,
                                                   int gbase, int Cg) {
  int bid = blockIdx.x;
  int gw = bid % Cg, eb = bid / Cg;
  size_t ebase = (size_t)(gbase + gw) * 2 * EE;
  int e = eb * 256 + threadIdx.x;
  int src = edges[ebase + e];
  int dst = edges[ebase + EE + e];
  int pos = atomicAdd(&cursor[gw * NN + dst], 1);   // absolute slot
  csr[(size_t)gw * EE + pos] = (unsigned short)src;
}

// ---------------- W^T hi/lo precompute ----------------

__global__ __launch_bounds__(256) void wtprep_kernel(const float* __restrict__ W0,
                                                     const float* __restrict__ W1,
                                                     const float* __restrict__ W2,
                                                     __bf16* __restrict__ wt) {
  const float* Wl[3] = {W0, W1, W2};
  int l = blockIdx.x;
  const float* W = Wl[l];
  __bf16* hi = wt + (size_t)l * 2 * F * F;
  __bf16* lo = hi + F * F;
  for (int idx = threadIdx.x; idx < F * F; idx += 256) {
    int k = idx >> 7, c = idx & 127;
    float f = W[idx];
    __bf16 h = (__bf16)f;
    hi[c * F + k] = h;                  // transposed: [col][k]
    lo[c * F + k] = (__bf16)(f - (float)h);
  }
}

// ---------------- W-stationary persistent-wave GEMM ----------------
// h1[gw][row][col] = bf16( (act[row] @ W)[col] * dinv[row] )
// Each wave owns a fixed 32-col group: B-frags (W^T hi/lo) live in VGPRs, loaded
// once. Swapped operands mfma(Wfrag, actfrag) -> lane holds one act-row (lane&15)
// and 4 consecutive output cols per acc reg -> direct 8B stores, no LDS/syncthreads.
// MODE 0: f32 activations (x), hi/lo A split, 3 MFMA terms.
// MODE 1: bf16 activations (exact in bf16), 2 MFMA terms.

template<int MODE>
__global__ __launch_bounds__(256) void gemm_kernel(const void* __restrict__ actp,
                                                   const __bf16* __restrict__ wt,
                                                   const float* __restrict__ dinv,
                                                   unsigned short* __restrict__ h1,
                                                   int gbase, int Cg) {
  int w = threadIdx.x >> 6, l = threadIdx.x & 63;
  int wave = blockIdx.x * 4 + w;
  int cg  = wave & 3;                 // col-group: cols [cg*32, cg*32+32)
  int i16 = l & 15, kq = l >> 4;      // frag index-in-tile, k-quarter

  bf16x8 Bhi[2][4], Blo[2][4];        // stationary W^T frags: 64 VGPRs
  #pragma unroll
  for (int t2 = 0; t2 < 2; ++t2) {
    int col = cg * 32 + t2 * 16 + i16;
    #pragma unroll
    for (int ks = 0; ks < 4; ++ks) {
      Bhi[t2][ks] = *(const bf16x8*)(wt +         (size_t)col * F + ks * 32 + kq * 8);
      Blo[t2][ks] = *(const bf16x8*)(wt + F * F + (size_t)col * F + ks * 32 + kq * 8);
    }
  }

  int ntask = Cg * 3125 * 4;          // 50000/16 chunks per graph x 4 col-groups
  int stride = gridDim.x * 4;         // multiple of 4 -> cg invariant per wave
  for (int task = wave; task < ntask; task += stride) {
    int chunk = task >> 2;
    int gw = chunk / 3125, ch = chunk - gw * 3125;
    int row = ch * 16 + i16;
    size_t rbase = (size_t)row * F + kq * 8;

    f32x4 acc0 = {0.f, 0.f, 0.f, 0.f}, acc1 = acc0;
    if (MODE == 0) {
      const float* ag = (const float*)actp + (size_t)(gbase + gw) * NN * F;
      #pragma unroll
      for (int ks = 0; ks < 4; ++ks) {
        float4_t v0 = *(const float4_t*)(ag + rbase + ks * 32);
        float4_t v1 = *(const float4_t*)(ag + rbase + ks * 32 + 4);
        bf16x8 ahi, alo;
        #pragma unroll
        for (int j = 0; j < 4; ++j) {
          __bf16 h0 = (__bf16)v0[j], h1v = (__bf16)v1[j];
          ahi[j] = h0;     ahi[j + 4] = h1v;
          alo[j] = (__bf16)(v0[j] - (float)h0);
          alo[j + 4] = (__bf16)(v1[j] - (float)h1v);
        }
        acc0 = __builtin_amdgcn_mfma_f32_16x16x32_bf16(Bhi[0][ks], ahi, acc0, 0, 0, 0);
        acc0 = __builtin_amdgcn_mfma_f32_16x16x32_bf16(Blo[0][ks], ahi, acc0, 0, 0, 0);
        acc0 = __builtin_amdgcn_mfma_f32_16x16x32_bf16(Bhi[0][ks], alo, acc0, 0, 0, 0);
        acc1 = __builtin_amdgcn_mfma_f32_16x16x32_bf16(Bhi[1][ks], ahi, acc1, 0, 0, 0);
        acc1 = __builtin_amdgcn_mfma_f32_16x16x32_bf16(Blo[1][ks], ahi, acc1, 0, 0, 0);
        acc1 = __builtin_amdgcn_mfma_f32_16x16x32_bf16(Bhi[1][ks], alo, acc1, 0, 0, 0);
      }
    } else {
      const unsigned short* ag = (const unsigned short*)actp + (size_t)gw * NN * F;
      #pragma unroll
      for (int ks = 0; ks < 4; ++ks) {
        bf16x8 a = *(const bf16x8*)((const __bf16*)ag + rbase + ks * 32);
        acc0 = __builtin_amdgcn_mfma_f32_16x16x32_bf16(Bhi[0][ks], a, acc0, 0, 0, 0);
        acc0 = __builtin_amdgcn_mfma_f32_16x16x32_bf16(Blo[0][ks], a, acc0, 0, 0, 0);
        acc1 = __builtin_amdgcn_mfma_f32_16x16x32_bf16(Bhi[1][ks], a, acc1, 0, 0, 0);
        acc1 = __builtin_amdgcn_mfma_f32_16x16x32_bf16(Blo[1][ks], a, acc1, 0, 0, 0);
      }
    }
    // D^T frag: lane holds act-row (l&15), output cols (kq*4 + q) within each tile
    float di = (dinv + (size_t)gw * NN)[row];
    unsigned short* hr = h1 + (size_t)gw * NN * F + (size_t)row * F + cg * 32 + kq * 4;
    u16x4 o0, o1;
    #pragma unroll
    for (int q = 0; q < 4; ++q) { o0[q] = f2bf(acc0[q] * di); o1[q] = f2bf(acc1[q] * di); }
    *(u16x4*)hr = o0;
    *(u16x4*)(hr + 16) = o1;
  }
}

// ---------------- aggregation (unchanged from r8): 16 lanes/node, u16x8, ILP-4 ----

template<int FIN>
__global__ __launch_bounds__(256) void agg_kernel(const unsigned short* __restrict__ h1,
                                                  const unsigned short* __restrict__ csr,
                                                  const int* __restrict__ row_off,
                                                  const float* __restrict__ dinv,
                                                  const float* __restrict__ bias,
                                                  void* __restrict__ outp, int gbase, int Cg) {
  int bid = blockIdx.x;
  int gw = bid % Cg, xb = bid / Cg;
  const unsigned short* hg = h1 + (size_t)gw * NN * F;
  const unsigned short* cs = csr + (size_t)gw * EE;
  const int*   ro = row_off + gw * (NN + 1);
  const float* dv = dinv + (size_t)gw * NN;

  int grp = threadIdx.x >> 4, lane = threadIdx.x & 15;
  int node = xb * 16 + grp;                   // 3125*16 == 50000 exact
  int e0 = ro[node], e1 = ro[node + 1];
  float di = dv[node];
  f32x4 a0 = {0.f, 0.f, 0.f, 0.f}, b0 = a0, a1 = a0, b1 = a0;
  addrow(a0, b0, *(const u16x8*)(hg + (size_t)node * F + lane * 8));   // self (scaled)
  int e = e0;
  for (; e + 3 < e1; e += 4) {
    int s0 = cs[e], s1 = cs[e + 1], s2 = cs[e + 2], s3 = cs[e + 3];
    u16x8 v0 = *(const u16x8*)(hg + (size_t)s0 * F + lane * 8);
    u16x8 v1 = *(const u16x8*)(hg + (size_t)s1 * F + lane * 8);
    u16x8 v2 = *(const u16x8*)(hg + (size_t)s2 * F + lane * 8);
    u16x8 v3 = *(const u16x8*)(hg + (size_t)s3 * F + lane * 8);
    addrow(a0, b0, v0);
    addrow(a1, b1, v1);
    addrow(a0, b0, v2);
    addrow(a1, b1, v3);
  }
  for (; e < e1; ++e) {
    int s = cs[e];
    addrow(a0, b0, *(const u16x8*)(hg + (size_t)s * F + lane * 8));
  }
  f32x4 ra = a0 + a1, rb = b0 + b1;
  float4_t bb0 = *(const float4_t*)(bias + lane * 8);
  float4_t bb1 = *(const float4_t*)(bias + lane * 8 + 4);
  #pragma unroll
  for (int j = 0; j < 4; ++j) {
    ra[j] = fmaxf(fmaf(ra[j], di, bb0[j]), 0.f);
    rb[j] = fmaxf(fmaf(rb[j], di, bb1[j]), 0.f);
  }
  if (FIN) {
    float* og = (float*)outp + (size_t)(gbase + gw) * NN * F + (size_t)node * F + lane * 8;
    *(float4_t*)og = ra;
    *(float4_t*)(og + 4) = rb;
  } else {
    u16x8 o;
    #pragma unroll
    for (int j = 0; j < 4; ++j) { o[j] = f2bf(ra[j]); o[j + 4] = f2bf(rb[j]); }
    unsigned short* og = (unsigned short*)outp + (size_t)gw * NN * F + (size_t)node * F + lane * 8;
    *(u16x8*)og = o;
  }
}

// ---------------- host launch ----------------

extern "C" void kernel_launch(void* const* d_in, const int* in_sizes, int n_in,
                              void* d_out, int out_size, void* d_ws, size_t ws_size,
                              hipStream_t stream) {
  const float* x     = (const float*)d_in[0];
  const int*   edges = (const int*)d_in[1];
  const float* Ws[3] = {(const float*)d_in[2], (const float*)d_in[4], (const float*)d_in[6]};
  const float* bs[3] = {(const float*)d_in[3], (const float*)d_in[5], (const float*)d_in[7]};
  float* out = (float*)d_out;

  size_t sz_h1  = (size_t)NN * F * 2;           // 12.8 MB bf16 per graph (x2 buffers)
  size_t sz_wt  = (size_t)3 * 2 * F * F * 2;
  size_t sz_csr = (size_t)EE * 2;               // u16 CSR
  size_t sz_deg = (size_t)NN * 4;
  size_t sz_dv  = (size_t)NN * 4;
  size_t sz_ro  = (size_t)(NN + 1) * 4;
  size_t per_g  = 2 * sz_h1 + sz_csr + sz_deg + sz_dv + sz_ro;  // ~27.8 MB

  int CB = (int)((ws_size > sz_wt ? ws_size - sz_wt : 0) / per_g);
  if (CB < 1) CB = 1;
  if (CB > G) CB = G;

  char* p = (char*)d_ws;
  unsigned short* h1      = (unsigned short*)p;  p += sz_h1 * CB;
  unsigned short* actb    = (unsigned short*)p;  p += sz_h1 * CB;
  __bf16*         wt      = (__bf16*)p;          p += sz_wt;
  unsigned short* csr     = (unsigned short*)p;  p += sz_csr * CB;
  int*            deg     = (int*)p;             p += sz_deg * CB;   // -> cursor after scan
  float*          dinv    = (float*)p;           p += sz_dv  * CB;
  int*            row_off = (int*)p;

  wtprep_kernel<<<3, 256, 0, stream>>>(Ws[0], Ws[1], Ws[2], wt);

  int nblk_e = EE / 256;         // 3125
  int nblk_m = 2048;             // persistent-wave GEMM grid (8192 waves)
  int nblk_a = NN / 16;          // 3125

  for (int gb = 0; gb < G; gb += CB) {
    int Cg = G - gb < CB ? G - gb : CB;
    hipMemsetAsync(deg, 0, sz_deg * CB, stream);
    deg_kernel <<<nblk_e * Cg, 256, 0, stream>>>(edges, deg, gb, Cg);
    scan_kernel<<<Cg, 1024, 0, stream>>>(deg, row_off, dinv);
    fill_kernel<<<nblk_e * Cg, 256, 0, stream>>>(edges, deg, csr, gb, Cg);

    // layer 0 (f32 x input)
    gemm_kernel<0><<<nblk_m, 256, 0, stream>>>(x, wt, dinv, h1, gb, Cg);
    agg_kernel<0><<<nblk_a * Cg, 256, 0, stream>>>(h1, csr, row_off, dinv, bs[0], actb, gb, Cg);
    // layer 1 (bf16 activations)
    gemm_kernel<1><<<nblk_m, 256, 0, stream>>>(actb, wt + 2 * F * F, dinv, h1, gb, Cg);
    agg_kernel<0><<<nblk_a * Cg, 256, 0, stream>>>(h1, csr, row_off, dinv, bs[1], actb, gb, Cg);
    // layer 2 (bf16 activations)
    gemm_kernel<1><<<nblk_m, 256, 0, stream>>>(actb, wt + 4 * F * F, dinv, h1, gb, Cg);
    agg_kernel<1><<<nblk_a * Cg, 256, 0, stream>>>(h1, csr, row_off, dinv, bs[2], out, gb, Cg);
  }
}